// Round 12
// baseline (531.932 us; speedup 1.0000x reference)
//
#include <hip/hip_runtime.h>
#include <cstddef>

constexpr int N0 = 16384, N1 = 4096, N2 = 1024, N3 = 256;
constexpr int E0 = 6 * N0, E1 = 6 * N1, E2 = 6 * N2, E3 = 6 * N3;
constexpr int ETOT = E0 + E1 + E2 + E3; // 129024
constexpr int LOCN = 32 * N0;           // 524288

// ---- workspace layout (4-byte units) ----
constexpr size_t O_CNT  = 0;        // 21760 ints (g0@0, g1@16384, g2@20480, g3@21504)
constexpr size_t O_STAT = 21760;    // 384 floats (6 slots x 64) -- zeroed with cnt
constexpr size_t O_BK   = 22144;    // buckets: A0@0, A1@524288, A2@655360, A3@688128
constexpr size_t O_YL0  = 720896;   // 524288
constexpr size_t O_XL1  = O_YL0 + 524288;
constexpr size_t O_YL1  = O_XL1 + 524288;
constexpr size_t O_XL2  = O_YL1 + 524288;
constexpr size_t O_YL2  = O_XL2 + 524288;
constexpr size_t O_XL3  = O_YL2 + 524288;
constexpr size_t O_YG0  = O_XL3 + 524288;  // 8192
constexpr size_t O_XG1  = O_YG0 + 8192;
constexpr size_t O_XWG1 = O_XG1 + 8192;
constexpr size_t O_YG1  = O_XWG1 + 8192;   // 32768
constexpr size_t O_XG2  = O_YG1 + 32768;
constexpr size_t O_XWG2 = O_XG2 + 32768;
constexpr size_t O_YG2  = O_XWG2 + 32768;  // 131072
constexpr size_t O_XG3  = O_YG2 + 131072;  // 131072
constexpr size_t O_YG3  = O_XG3 + 131072;  // 49152
constexpr size_t O_XLZ  = O_YG3 + 49152;   // 128

struct Params {
    const float *z, *lin_w, *lin_b, *loc_w, *loc_b, *Wg, *bg, *Wg3, *bg3;
    const float *Wl, *bl, *Wl3, *bl3, *gam_g, *bet_g, *gam_l, *bet_l;
    const float *U0, *U1, *U2, *U3;
    const int *A0, *A1, *A2, *A3;
    float* ws;
    float* out;
};

// ============ bucket-CSR fill (one pass, all 4 graphs) ============
__device__ void fill_edges(const Params& P, int rb, int nrb) {
    int* cnt = (int*)(P.ws + O_CNT);
    int* bk  = (int*)(P.ws + O_BK);
    for (int e = rb * 256 + threadIdx.x; e < ETOT; e += nrb * 256) {
        const int* A; int E, co, bo; int x = e;
        if (x < E0)              { A = P.A0; E = E0; co = 0;     bo = 0; }
        else if ((x -= E0) < E1) { A = P.A1; E = E1; co = 16384; bo = 524288; }
        else if ((x -= E1) < E2) { A = P.A2; E = E2; co = 20480; bo = 655360; }
        else { x -= E2;            A = P.A3; E = E3; co = 21504; bo = 688128; }
        int s = A[x], d = A[E + x];
        int slot = atomicAdd(cnt + co + d, 1);
        if (slot < 32) bk[bo + d * 32 + slot] = s;
    }
}

// ============ fused matvec + @Wl0 chunk; xlz from LDS-compute or ws ============
template <bool SELF_XLZ>
__device__ void matvec_y(const Params& P, int mb, float* sm) {
    float* xs   = sm;          // 128 (xlz)
    float* xrow = sm + 128;    // 1024
    float* Wl   = sm + 1152;   // 1024
    float* zl   = sm + 2176;   // 128 (only SELF_XLZ)
    int t = threadIdx.x;
    for (int i = t; i < 1024; i += 256) Wl[i] = P.Wl[i];
    if (SELF_XLZ) {
        if (t < 128) zl[t] = P.z[t];
        __syncthreads();
        if (t < 128) {
            float s = P.lin_b[32 + t];
#pragma unroll 8
            for (int k = 0; k < 128; k++) s += zl[k] * P.lin_w[k * 160 + 32 + t];
            xs[t] = s;
        }
    } else {
        if (t < 128) xs[t] = (P.ws + O_XLZ)[t];
    }
    __syncthreads();
    size_t j0 = (size_t)mb * 1024 + t * 4;
    float4 acc = *(const float4*)(P.loc_b + j0);
#pragma unroll 8
    for (int k = 0; k < 128; k++) {
        float xk = xs[k];
        float4 w = *(const float4*)(P.loc_w + (size_t)k * LOCN + j0);
        acc.x += xk * w.x; acc.y += xk * w.y; acc.z += xk * w.z; acc.w += xk * w.w;
    }
    *(float4*)(xrow + t * 4) = acc;
    __syncthreads();
    float* yl0 = P.ws + O_YL0;
#pragma unroll
    for (int q = 0; q < 4; q++) {
        int idx = q * 256 + t;
        int nn = idx >> 5, f = idx & 31;
        float s = 0.f;
        const float* xr = xrow + nn * 32;
#pragma unroll
        for (int k = 0; k < 32; k++) s += xr[k] * Wl[k * 32 + f];
        yl0[(size_t)mb * 1024 + idx] = s;
    }
}

// ============ lin head: xlz->ws, xw0, rank-1 U3 level -> YG0 ============
__device__ void lin_u3(const Params& P, float* sm) {
    float* zl  = sm;         // 128
    float* xl  = sm + 128;   // 160
    float* xw0 = sm + 288;   // 32
    int t = threadIdx.x;
    if (t < 128) zl[t] = P.z[t];
    __syncthreads();
    if (t < 160) {
        float s = P.lin_b[t];
        for (int k = 0; k < 128; k++) s += zl[k] * P.lin_w[k * 160 + t];
        xl[t] = s;
    }
    __syncthreads();
    if (t < 128) (P.ws + O_XLZ)[t] = xl[32 + t];
    if (t < 32) {
        float s = 0.f;
        for (int k = 0; k < 32; k++) s += xl[k] * P.Wg[k * 32 + t];
        xw0[t] = s;
    }
    __syncthreads();
    float rs = 0.f;
    for (int k = 0; k < 64; k++) rs += P.U3[t * 64 + k];
    float* y = P.ws + O_YG0;
    for (int f = 0; f < 32; f++) y[t * 32 + f] = rs * xw0[f];
}

// ============ bucket gather (F=32) + bias + BN stats ============
template <int WPB>
__device__ void gatherB(const int* cnt, const int* bk, const float* y,
                        const float* bias, int n, float* xout, float* stats,
                        int rb, int nrb, float* sm) {
    int t = threadIdx.x, f = t & 31, half = (t >> 5) & 1, w = t >> 6;
    float bf = bias[f];
    float s = 0.f, ss = 0.f;
    for (int node = rb * WPB + w; node < n; node += nrb * WPB) {
        int c = cnt[node];
        int cl = c < 32 ? c : 32;
        const int* b = bk + (size_t)node * 32;
        float a = half ? 0.f : y[(size_t)node * 32 + f];
        for (int r = half; r < cl; r += 2)
            a += y[(size_t)b[r] * 32 + f];
        a += __shfl_down(a, 32, 64);
        if (!half) {
            float v = a / (float)(c + 1) + bf;
            xout[(size_t)node * 32 + f] = v;
            s += v; ss += v * v;
        }
    }
    if (t < 64) sm[t] = 0.f;
    __syncthreads();
    if (!half) { atomicAdd(sm + f, s); atomicAdd(sm + 32 + f, ss); }
    __syncthreads();
    if (t < 64) atomicAdd(stats + t, sm[t]);
}

// ============ BN + leakyReLU + row @ W(32xFO), 512 threads ============
template <int FO>
__device__ void bnxw512(const float* xin, const float* stats, const float* gam,
                        const float* bet, const float* W, float invn, int n,
                        float* out, int rb, float* sm) {
    float* Wl = sm;
    float* sc = sm + 32 * FO;
    float* sh = sc + 32;
    int t = threadIdx.x;
    for (int i = t; i < 32 * FO; i += 512) Wl[i] = W[i];
    if (t < 32) {
        float mu = stats[t] * invn;
        float var = stats[32 + t] * invn - mu * mu;
        float rs = rsqrtf(var + 1e-5f);
        float scv = rs * gam[t];
        sc[t] = scv; sh[t] = bet[t] - mu * scv;
    }
    __syncthreads();
    int node = rb * 512 + t;
    if (node < n) {
        float x[32];
        const float4* xp = (const float4*)(xin + (size_t)node * 32);
#pragma unroll
        for (int j = 0; j < 8; j++) {
            float4 v = xp[j];
            x[4 * j] = v.x; x[4 * j + 1] = v.y; x[4 * j + 2] = v.z; x[4 * j + 3] = v.w;
        }
#pragma unroll
        for (int k = 0; k < 32; k++) {
            float v = sc[k] * x[k] + sh[k];
            x[k] = v > 0.f ? v : 0.01f * v;
        }
        float yv[FO];
#pragma unroll
        for (int q = 0; q < FO; q++) {
            float s = 0.f;
#pragma unroll
            for (int k = 0; k < 32; k++) s += x[k] * Wl[k * FO + q];
            yv[q] = s;
        }
        float* yp = out + (size_t)node * FO;
#pragma unroll
        for (int q = 0; q < FO; q++) yp[q] = yv[q];
    }
}

// 256-thread variant for n=256 (bn_g0, one block)
__device__ void bnxw256_g0(const Params& P, float* sm) {
    float* ws = P.ws;
    const float* stats = ws + O_STAT;        // slot 0
    float* Wl = sm;
    float* sc = sm + 1024;
    float* sh = sc + 32;
    int t = threadIdx.x;
    for (int i = t; i < 1024; i += 256) Wl[i] = P.Wg[1024 + i];
    if (t < 32) {
        float invn = 1.f / N3;
        float mu = stats[t] * invn;
        float var = stats[32 + t] * invn - mu * mu;
        float rs = rsqrtf(var + 1e-5f);
        float scv = rs * P.gam_g[t];
        sc[t] = scv; sh[t] = P.bet_g[t] - mu * scv;
    }
    __syncthreads();
    const float* xin = ws + O_XG1;
    float x[32];
    const float4* xp = (const float4*)(xin + (size_t)t * 32);
#pragma unroll
    for (int j = 0; j < 8; j++) {
        float4 v = xp[j];
        x[4 * j] = v.x; x[4 * j + 1] = v.y; x[4 * j + 2] = v.z; x[4 * j + 3] = v.w;
    }
#pragma unroll
    for (int k = 0; k < 32; k++) {
        float v = sc[k] * x[k] + sh[k];
        x[k] = v > 0.f ? v : 0.01f * v;
    }
    float* yp = ws + O_XWG1 + (size_t)t * 32;
#pragma unroll
    for (int q = 0; q < 32; q++) {
        float s = 0.f;
#pragma unroll
        for (int k = 0; k < 32; k++) s += x[k] * Wl[k * 32 + q];
        yp[q] = s;
    }
}

// ============ y = U(64 rows) @ xw(m x 32), 512 threads ============
__device__ void gemm512(const float* U, const float* xw, int m, float* y,
                        int rb, float* sm) {
    float* ut = sm;          // 64*64
    float* xt = sm + 4096;   // 64*32
    int t = threadIdx.x, f = t & 31, rg = t >> 5;
    int r0 = rb * 64;
    float a0 = 0, a1 = 0, a2 = 0, a3 = 0;
    for (int k0 = 0; k0 < m; k0 += 64) {
        {
            int row = t >> 3, c0 = (t & 7) * 8;
            const float* src = U + (size_t)(r0 + row) * m + k0 + c0;
            *(float4*)(ut + row * 64 + c0) = *(const float4*)src;
            *(float4*)(ut + row * 64 + c0 + 4) = *(const float4*)(src + 4);
        }
        {
            int kk = t >> 3, c0 = (t & 7) * 4;
            *(float4*)(xt + kk * 32 + c0) =
                *(const float4*)(xw + (size_t)(k0 + kk) * 32 + c0);
        }
        __syncthreads();
#pragma unroll
        for (int kk = 0; kk < 64; kk++) {
            float xv = xt[kk * 32 + f];
            a0 += ut[rg * 64 + kk] * xv;
            a1 += ut[(rg + 16) * 64 + kk] * xv;
            a2 += ut[(rg + 32) * 64 + kk] * xv;
            a3 += ut[(rg + 48) * 64 + kk] * xv;
        }
        __syncthreads();
    }
    y[(size_t)(r0 + rg) * 32 + f] = a0;
    y[(size_t)(r0 + rg + 16) * 32 + f] = a1;
    y[(size_t)(r0 + rg + 32) * 32 + f] = a2;
    y[(size_t)(r0 + rg + 48) * 32 + f] = a3;
}

// ================= D1: mv[0:191) | bucket-fill | lin+U3  (256) ============
__global__ void __launch_bounds__(256) k_d1(Params P) {
    __shared__ float sm[2304];
    int bid = blockIdx.x;
    if (bid < 191)      matvec_y<true>(P, bid, sm);
    else if (bid < 255) fill_edges(P, bid - 191, 64);
    else                lin_u3(P, sm);
}

// ================= D2: mv[191:443) | g_g0(A3)  (256) ============
__global__ void __launch_bounds__(256) k_d2(Params P) {
    __shared__ float sm[2304];
    int bid = blockIdx.x;
    float* ws = P.ws;
    if (bid < 252) {
        matvec_y<false>(P, 191 + bid, sm);
    } else {
        const int* cnt = (int*)(ws + O_CNT);
        const int* bk  = (int*)(ws + O_BK);
        gatherB<4>(cnt + 21504, bk + 688128, ws + O_YG0, P.bg, N3,
                   ws + O_XG1, ws + O_STAT, bid - 252, 4, sm);
    }
}

// ================= D3: mv[443:512) | bn_g0  (70) ============
__global__ void __launch_bounds__(256) k_d3(Params P) {
    __shared__ float sm[2304];
    int bid = blockIdx.x;
    if (bid < 69) matvec_y<false>(P, 443 + bid, sm);
    else          bnxw256_g0(P, sm);
}

// ================= D4: g_l0 | gemmU2  (256 x 512) ============
__global__ void __launch_bounds__(512) k_d4(Params P) {
    __shared__ float sm[6144];
    int bid = blockIdx.x;
    float* ws = P.ws;
    const int* cnt = (int*)(ws + O_CNT);
    const int* bk  = (int*)(ws + O_BK);
    if (bid < 240)
        gatherB<8>(cnt, bk, ws + O_YL0, P.bl, N0, ws + O_XL1,
                   ws + O_STAT + 192, bid, 240, sm);
    else
        gemm512(P.U2, ws + O_XWG1, 256, ws + O_YG1, bid - 240, sm);
}

// ================= D5: bn_l0 | g_g1(A2)  (48 x 512) ============
__global__ void __launch_bounds__(512) k_d5(Params P) {
    __shared__ float sm[1152];
    int bid = blockIdx.x;
    float* ws = P.ws;
    const int* cnt = (int*)(ws + O_CNT);
    const int* bk  = (int*)(ws + O_BK);
    if (bid < 32)
        bnxw512<32>(ws + O_XL1, ws + O_STAT + 192, P.gam_l, P.bet_l, P.Wl + 1024,
                    1.f / N0, N0, ws + O_YL1, bid, sm);
    else
        gatherB<8>(cnt + 20480, bk + 655360, ws + O_YG1, P.bg + 32, N2,
                   ws + O_XG2, ws + O_STAT + 64, bid - 32, 16, sm);
}

// ================= D6: g_l1 | bn_g1  (242 x 512) ============
__global__ void __launch_bounds__(512) k_d6(Params P) {
    __shared__ float sm[1152];
    int bid = blockIdx.x;
    float* ws = P.ws;
    const int* cnt = (int*)(ws + O_CNT);
    const int* bk  = (int*)(ws + O_BK);
    if (bid < 240)
        gatherB<8>(cnt, bk, ws + O_YL1, P.bl + 32, N0, ws + O_XL2,
                   ws + O_STAT + 256, bid, 240, sm);
    else
        bnxw512<32>(ws + O_XG2, ws + O_STAT + 64, P.gam_g + 32, P.bet_g + 32,
                    P.Wg + 2048, 1.f / N2, N2, ws + O_XWG2, bid - 240, sm);
}

// ================= D7: bn_l1 | gemmU1  (96 x 512) ============
__global__ void __launch_bounds__(512) k_d7(Params P) {
    __shared__ float sm[6144];
    int bid = blockIdx.x;
    float* ws = P.ws;
    if (bid < 32)
        bnxw512<32>(ws + O_XL2, ws + O_STAT + 256, P.gam_l + 32, P.bet_l + 32,
                    P.Wl + 2048, 1.f / N0, N0, ws + O_YL2, bid, sm);
    else
        gemm512(P.U1, ws + O_XWG2, 1024, ws + O_YG2, bid - 32, sm);
}

// ================= D8: g_l2 | g_g2(A1)  (256 x 512) ============
__global__ void __launch_bounds__(512) k_d8(Params P) {
    __shared__ float sm[64];
    int bid = blockIdx.x;
    float* ws = P.ws;
    const int* cnt = (int*)(ws + O_CNT);
    const int* bk  = (int*)(ws + O_BK);
    if (bid < 240)
        gatherB<8>(cnt, bk, ws + O_YL2, P.bl + 64, N0, ws + O_XL3,
                   ws + O_STAT + 320, bid, 240, sm);
    else
        gatherB<8>(cnt + 16384, bk + 524288, ws + O_YG2, P.bg + 64, N1,
                   ws + O_XG3, ws + O_STAT + 128, bid - 240, 16, sm);
}

// ================= D9: [bn_g2 folded] + U0 stream  (256 x 256) ============
__global__ void __launch_bounds__(256) k_d9(Params P) {
    __shared__ float pl[12288];
    __shared__ float w3[96];
    __shared__ float sc[32], sh[32];
    int t = threadIdx.x;
    float* ws = P.ws;
    if (t < 96) w3[t] = P.Wg3[t];
    if (t >= 128 && t < 160) {
        int q = t - 128;
        float invn = 1.f / N1;
        const float* stats = ws + O_STAT + 128;
        float mu = stats[q] * invn;
        float var = stats[32 + q] * invn - mu * mu;
        float rs = rsqrtf(var + 1e-5f);
        float scv = rs * P.gam_g[64 + q];
        sc[q] = scv; sh[q] = P.bet_g[64 + q] - mu * scv;
    }
    __syncthreads();
    // compute xw3 (4096 x 3) into swizzled LDS
    const float* xg3 = ws + O_XG3;
#pragma unroll 2
    for (int q = 0; q < 16; q++) {
        int node = q * 256 + t;
        float x[32];
        const float4* xp = (const float4*)(xg3 + (size_t)node * 32);
#pragma unroll
        for (int j = 0; j < 8; j++) {
            float4 v = xp[j];
            x[4 * j] = v.x; x[4 * j + 1] = v.y; x[4 * j + 2] = v.z; x[4 * j + 3] = v.w;
        }
#pragma unroll
        for (int k = 0; k < 32; k++) {
            float v = sc[k] * x[k] + sh[k];
            x[k] = v > 0.f ? v : 0.01f * v;
        }
        int base = ((node & 3) << 10) + (node >> 2);
#pragma unroll
        for (int h = 0; h < 3; h++) {
            float s = 0.f;
#pragma unroll
            for (int k = 0; k < 32; k++) s += x[k] * w3[k * 3 + h];
            pl[h * 4096 + base] = s;
        }
    }
    __syncthreads();
    float* y = ws + O_YG3;
    int w = t >> 6, lane = t & 63;
    for (int it = 0; it < 4; it++) {
        for (int rr = 0; rr < 4; rr++) {
            int row = it * 4096 + blockIdx.x * 16 + w * 4 + rr;
            const float4* up = (const float4*)(P.U0 + (size_t)row * 4096);
            float a0 = 0, a1 = 0, a2 = 0;
#pragma unroll 4
            for (int c = 0; c < 16; c++) {
                float4 u = up[c * 64 + lane];
                int b = c * 64 + lane;
                a0 += u.x * pl[b]        + u.y * pl[1024 + b]  + u.z * pl[2048 + b]   + u.w * pl[3072 + b];
                a1 += u.x * pl[4096 + b] + u.y * pl[5120 + b]  + u.z * pl[6144 + b]   + u.w * pl[7168 + b];
                a2 += u.x * pl[8192 + b] + u.y * pl[9216 + b]  + u.z * pl[10240 + b]  + u.w * pl[11264 + b];
            }
            for (int o = 32; o; o >>= 1) {
                a0 += __shfl_down(a0, o, 64);
                a1 += __shfl_down(a1, o, 64);
                a2 += __shfl_down(a2, o, 64);
            }
            if (lane == 0) { y[row * 3] = a0; y[row * 3 + 1] = a1; y[row * 3 + 2] = a2; }
        }
    }
}

// ========= D10: final combine; [bnxw_l2 folded] one thread per node (64 x 256) ==
__global__ void __launch_bounds__(256) k_d10(Params P) {
    __shared__ float wl3[96];
    __shared__ float sc[32], sh[32];
    __shared__ float bias[6]; // bl3[0..2], bg3[0..2]
    int t = threadIdx.x;
    float* ws = P.ws;
    if (t < 96) wl3[t] = P.Wl3[t];
    if (t >= 128 && t < 160) {
        int q = t - 128;
        float invn = 1.f / N0;
        const float* stats = ws + O_STAT + 320;
        float mu = stats[q] * invn;
        float var = stats[32 + q] * invn - mu * mu;
        float rs = rsqrtf(var + 1e-5f);
        float scv = rs * P.gam_l[64 + q];
        sc[q] = scv; sh[q] = P.bet_l[64 + q] - mu * scv;
    }
    if (t >= 96 && t < 99)  bias[t - 96] = P.bl3[t - 96];
    if (t >= 99 && t < 102) bias[t - 96] = P.bg3[t - 99];
    __syncthreads();
    int node = blockIdx.x * 256 + t;
    const int* cnt = (int*)(ws + O_CNT);
    const int* bk  = (int*)(ws + O_BK) + (size_t)node * 32;
    const float* xl3 = ws + O_XL3;
    const float* yg3 = ws + O_YG3;
    int c = cnt[node];
    int cl = c < 32 ? c : 32;
    float al0 = 0, al1 = 0, al2 = 0, ag0 = 0, ag1 = 0, ag2 = 0;
    int src = node;
    for (int e = -1; e < cl; e++) {
        if (e >= 0) src = bk[e];
        float x[32];
        const float4* xp = (const float4*)(xl3 + (size_t)src * 32);
#pragma unroll
        for (int j = 0; j < 8; j++) {
            float4 v = xp[j];
            x[4 * j] = v.x; x[4 * j + 1] = v.y; x[4 * j + 2] = v.z; x[4 * j + 3] = v.w;
        }
        float s0 = 0, s1 = 0, s2 = 0;
#pragma unroll
        for (int k = 0; k < 32; k++) {
            float v = sc[k] * x[k] + sh[k];
            v = v > 0.f ? v : 0.01f * v;
            s0 += v * wl3[k * 3];
            s1 += v * wl3[k * 3 + 1];
            s2 += v * wl3[k * 3 + 2];
        }
        al0 += s0; al1 += s1; al2 += s2;
        ag0 += yg3[src * 3];
        ag1 += yg3[src * 3 + 1];
        ag2 += yg3[src * 3 + 2];
    }
    float inv = 1.f / (float)(c + 1);
    P.out[node * 3]     = 0.01f * (ag0 * inv + bias[3]) + 0.99f * (al0 * inv + bias[0]);
    P.out[node * 3 + 1] = 0.01f * (ag1 * inv + bias[4]) + 0.99f * (al1 * inv + bias[1]);
    P.out[node * 3 + 2] = 0.01f * (ag2 * inv + bias[5]) + 0.99f * (al2 * inv + bias[2]);
}

extern "C" void kernel_launch(void* const* d_in, const int* in_sizes, int n_in,
                              void* d_out, int out_size, void* d_ws, size_t ws_size,
                              hipStream_t stream) {
    Params p;
    p.z     = (const float*)d_in[0];
    p.lin_w = (const float*)d_in[1];
    p.lin_b = (const float*)d_in[2];
    p.loc_w = (const float*)d_in[3];
    p.loc_b = (const float*)d_in[4];
    p.Wg    = (const float*)d_in[5];
    p.bg    = (const float*)d_in[8];
    p.Wg3   = (const float*)d_in[9];
    p.bg3   = (const float*)d_in[12];
    p.Wl    = (const float*)d_in[13];
    p.bl    = (const float*)d_in[16];
    p.Wl3   = (const float*)d_in[17];
    p.bl3   = (const float*)d_in[20];
    p.gam_g = (const float*)d_in[21];
    p.bet_g = (const float*)d_in[22];
    p.gam_l = (const float*)d_in[23];
    p.bet_l = (const float*)d_in[24];
    p.U0    = (const float*)d_in[25];
    p.U1    = (const float*)d_in[26];
    p.U2    = (const float*)d_in[27];
    p.U3    = (const float*)d_in[28];
    p.A0    = (const int*)d_in[29];
    p.A1    = (const int*)d_in[30];
    p.A2    = (const int*)d_in[31];
    p.A3    = (const int*)d_in[32];
    p.ws    = (float*)d_ws;
    p.out   = (float*)d_out;

    hipMemsetAsync(d_ws, 0, (21760 + 384) * 4, stream);  // cnt + stats
    k_d1 <<<256, 256, 0, stream>>>(p);
    k_d2 <<<256, 256, 0, stream>>>(p);
    k_d3 <<<70,  256, 0, stream>>>(p);
    k_d4 <<<256, 512, 0, stream>>>(p);
    k_d5 <<<48,  512, 0, stream>>>(p);
    k_d6 <<<242, 512, 0, stream>>>(p);
    k_d7 <<<96,  512, 0, stream>>>(p);
    k_d8 <<<256, 512, 0, stream>>>(p);
    k_d9 <<<256, 256, 0, stream>>>(p);
    k_d10<<<64,  256, 0, stream>>>(p);
}

// Round 13
// 401.225 us; speedup vs baseline: 1.3258x; 1.3258x over previous
//
#include <hip/hip_runtime.h>
#include <cstddef>

constexpr int N0 = 16384, N1 = 4096, N2 = 1024, N3 = 256;
constexpr int E0 = 6 * N0, E1 = 6 * N1, E2 = 6 * N2, E3 = 6 * N3;
constexpr int ETOT = E0 + E1 + E2 + E3; // 129024
constexpr int LOCN = 32 * N0;           // 524288

// ---- workspace layout (4-byte units) ----
constexpr size_t O_CNT  = 0;        // 21760 ints
constexpr size_t O_STAT = 21760;    // 384 floats (zeroed with cnt)
constexpr size_t O_BK   = 22144;    // buckets: A0@0, A1@524288, A2@655360, A3@688128
constexpr size_t O_YL0  = 720896;
constexpr size_t O_XL1  = O_YL0 + 524288;
constexpr size_t O_YL1  = O_XL1 + 524288;
constexpr size_t O_XL2  = O_YL1 + 524288;
constexpr size_t O_YL2  = O_XL2 + 524288;
constexpr size_t O_XL3  = O_YL2 + 524288;
constexpr size_t O_YL3  = O_XL3 + 524288;  // 49152
constexpr size_t O_YG0  = O_YL3 + 49152;   // 8192
constexpr size_t O_XG1  = O_YG0 + 8192;
constexpr size_t O_XWG1 = O_XG1 + 8192;
constexpr size_t O_YG1  = O_XWG1 + 8192;   // 32768
constexpr size_t O_XG2  = O_YG1 + 32768;
constexpr size_t O_XWG2 = O_XG2 + 32768;
constexpr size_t O_YG2  = O_XWG2 + 32768;  // 131072
constexpr size_t O_XG3  = O_YG2 + 131072;
constexpr size_t O_XW3  = O_XG3 + 131072;  // 12288
constexpr size_t O_YG3  = O_XW3 + 12288;   // 49152
constexpr size_t O_XLZ  = O_YG3 + 49152;   // 128

struct Params {
    const float *z, *lin_w, *lin_b, *loc_w, *loc_b, *Wg, *bg, *Wg3, *bg3;
    const float *Wl, *bl, *Wl3, *bl3, *gam_g, *bet_g, *gam_l, *bet_l;
    const float *U0, *U1, *U2, *U3;
    const int *A0, *A1, *A2, *A3;
    float* ws;
    float* out;
};

// ============ bucket-CSR fill (one pass, all 4 graphs) ============
__device__ void fill_edges(const Params& P, int rb, int nrb) {
    int* cnt = (int*)(P.ws + O_CNT);
    int* bk  = (int*)(P.ws + O_BK);
    for (int e = rb * 256 + threadIdx.x; e < ETOT; e += nrb * 256) {
        const int* A; int E, co, bo; int x = e;
        if (x < E0)              { A = P.A0; E = E0; co = 0;     bo = 0; }
        else if ((x -= E0) < E1) { A = P.A1; E = E1; co = 16384; bo = 524288; }
        else if ((x -= E1) < E2) { A = P.A2; E = E2; co = 20480; bo = 655360; }
        else { x -= E2;            A = P.A3; E = E3; co = 21504; bo = 688128; }
        int s = A[x], d = A[E + x];
        int slot = atomicAdd(cnt + co + d, 1);
        if (slot < 32) bk[bo + d * 32 + slot] = s;
    }
}

// ============ fused matvec + @Wl0 chunk ============
template <bool SELF_XLZ>
__device__ void matvec_y(const Params& P, int mb, float* sm) {
    float* xs   = sm;          // 128
    float* xrow = sm + 128;    // 1024
    float* Wl   = sm + 1152;   // 1024
    float* zl   = sm + 2176;   // 128
    int t = threadIdx.x;
    for (int i = t; i < 1024; i += 256) Wl[i] = P.Wl[i];
    if (SELF_XLZ) {
        if (t < 128) zl[t] = P.z[t];
        __syncthreads();
        if (t < 128) {
            float s = P.lin_b[32 + t];
#pragma unroll 8
            for (int k = 0; k < 128; k++) s += zl[k] * P.lin_w[k * 160 + 32 + t];
            xs[t] = s;
        }
    } else {
        if (t < 128) xs[t] = (P.ws + O_XLZ)[t];
    }
    __syncthreads();
    size_t j0 = (size_t)mb * 1024 + t * 4;
    float4 acc = *(const float4*)(P.loc_b + j0);
#pragma unroll 8
    for (int k = 0; k < 128; k++) {
        float xk = xs[k];
        float4 w = *(const float4*)(P.loc_w + (size_t)k * LOCN + j0);
        acc.x += xk * w.x; acc.y += xk * w.y; acc.z += xk * w.z; acc.w += xk * w.w;
    }
    *(float4*)(xrow + t * 4) = acc;
    __syncthreads();
    float* yl0 = P.ws + O_YL0;
#pragma unroll
    for (int q = 0; q < 4; q++) {
        int idx = q * 256 + t;
        int nn = idx >> 5, f = idx & 31;
        float s = 0.f;
        const float* xr = xrow + nn * 32;
#pragma unroll
        for (int k = 0; k < 32; k++) s += xr[k] * Wl[k * 32 + f];
        yl0[(size_t)mb * 1024 + idx] = s;
    }
}

// ============ lin head: xlz->ws, rank-1 U3 level -> YG0 ============
__device__ void lin_u3(const Params& P, float* sm) {
    float* zl  = sm;
    float* xl  = sm + 128;
    float* xw0 = sm + 288;
    int t = threadIdx.x;
    if (t < 128) zl[t] = P.z[t];
    __syncthreads();
    if (t < 160) {
        float s = P.lin_b[t];
        for (int k = 0; k < 128; k++) s += zl[k] * P.lin_w[k * 160 + t];
        xl[t] = s;
    }
    __syncthreads();
    if (t < 128) (P.ws + O_XLZ)[t] = xl[32 + t];
    if (t < 32) {
        float s = 0.f;
        for (int k = 0; k < 32; k++) s += xl[k] * P.Wg[k * 32 + t];
        xw0[t] = s;
    }
    __syncthreads();
    float rs = 0.f;
    for (int k = 0; k < 64; k++) rs += P.U3[t * 64 + k];
    float* y = P.ws + O_YG0;
    for (int f = 0; f < 32; f++) y[t * 32 + f] = rs * xw0[f];
}

// ============ bucket gather (F=32) + bias + BN stats ============
template <int WPB>
__device__ void gatherB(const int* cnt, const int* bk, const float* y,
                        const float* bias, int n, float* xout, float* stats,
                        int rb, int nrb, float* sm) {
    int t = threadIdx.x, f = t & 31, half = (t >> 5) & 1, w = t >> 6;
    float bf = bias[f];
    float s = 0.f, ss = 0.f;
    for (int node = rb * WPB + w; node < n; node += nrb * WPB) {
        int c = cnt[node];
        int cl = c < 32 ? c : 32;
        const int* b = bk + (size_t)node * 32;
        float a = half ? 0.f : y[(size_t)node * 32 + f];
        for (int r = half; r < cl; r += 2)
            a += y[(size_t)b[r] * 32 + f];
        a += __shfl_down(a, 32, 64);
        if (!half) {
            float v = a / (float)(c + 1) + bf;
            xout[(size_t)node * 32 + f] = v;
            s += v; ss += v * v;
        }
    }
    if (t < 64) sm[t] = 0.f;
    __syncthreads();
    if (!half) { atomicAdd(sm + f, s); atomicAdd(sm + 32 + f, ss); }
    __syncthreads();
    if (t < 64) atomicAdd(stats + t, sm[t]);
}

// ============ BN + leakyReLU + row @ W(32xFO), 512 threads ============
template <int FO>
__device__ void bnxw512(const float* xin, const float* stats, const float* gam,
                        const float* bet, const float* W, float invn, int n,
                        float* out, int rb, float* sm) {
    float* Wl = sm;
    float* sc = sm + 32 * FO;
    float* sh = sc + 32;
    int t = threadIdx.x;
    for (int i = t; i < 32 * FO; i += 512) Wl[i] = W[i];
    if (t < 32) {
        float mu = stats[t] * invn;
        float var = stats[32 + t] * invn - mu * mu;
        float rs = rsqrtf(var + 1e-5f);
        float scv = rs * gam[t];
        sc[t] = scv; sh[t] = bet[t] - mu * scv;
    }
    __syncthreads();
    int node = rb * 512 + t;
    if (node < n) {
        float x[32];
        const float4* xp = (const float4*)(xin + (size_t)node * 32);
#pragma unroll
        for (int j = 0; j < 8; j++) {
            float4 v = xp[j];
            x[4 * j] = v.x; x[4 * j + 1] = v.y; x[4 * j + 2] = v.z; x[4 * j + 3] = v.w;
        }
#pragma unroll
        for (int k = 0; k < 32; k++) {
            float v = sc[k] * x[k] + sh[k];
            x[k] = v > 0.f ? v : 0.01f * v;
        }
        float yv[FO];
#pragma unroll
        for (int q = 0; q < FO; q++) {
            float s = 0.f;
#pragma unroll
            for (int k = 0; k < 32; k++) s += x[k] * Wl[k * FO + q];
            yv[q] = s;
        }
        float* yp = out + (size_t)node * FO;
#pragma unroll
        for (int q = 0; q < FO; q++) yp[q] = yv[q];
    }
}

// 256-thread bn_g0 (one block, n=256)
__device__ void bnxw256_g0(const Params& P, float* sm) {
    float* ws = P.ws;
    const float* stats = ws + O_STAT;
    float* Wl = sm;
    float* sc = sm + 1024;
    float* sh = sc + 32;
    int t = threadIdx.x;
    for (int i = t; i < 1024; i += 256) Wl[i] = P.Wg[1024 + i];
    if (t < 32) {
        float invn = 1.f / N3;
        float mu = stats[t] * invn;
        float var = stats[32 + t] * invn - mu * mu;
        float rs = rsqrtf(var + 1e-5f);
        float scv = rs * P.gam_g[t];
        sc[t] = scv; sh[t] = P.bet_g[t] - mu * scv;
    }
    __syncthreads();
    const float* xin = ws + O_XG1;
    float x[32];
    const float4* xp = (const float4*)(xin + (size_t)t * 32);
#pragma unroll
    for (int j = 0; j < 8; j++) {
        float4 v = xp[j];
        x[4 * j] = v.x; x[4 * j + 1] = v.y; x[4 * j + 2] = v.z; x[4 * j + 3] = v.w;
    }
#pragma unroll
    for (int k = 0; k < 32; k++) {
        float v = sc[k] * x[k] + sh[k];
        x[k] = v > 0.f ? v : 0.01f * v;
    }
    float* yp = ws + O_XWG1 + (size_t)t * 32;
#pragma unroll
    for (int q = 0; q < 32; q++) {
        float s = 0.f;
#pragma unroll
        for (int k = 0; k < 32; k++) s += x[k] * Wl[k * 32 + q];
        yp[q] = s;
    }
}

// ============ y = U(64 rows) @ xw(m x 32), 512 threads ============
__device__ void gemm512(const float* U, const float* xw, int m, float* y,
                        int rb, float* sm) {
    float* ut = sm;          // 64*64
    float* xt = sm + 4096;   // 64*32
    int t = threadIdx.x, f = t & 31, rg = t >> 5;
    int r0 = rb * 64;
    float a0 = 0, a1 = 0, a2 = 0, a3 = 0;
    for (int k0 = 0; k0 < m; k0 += 64) {
        {
            int row = t >> 3, c0 = (t & 7) * 8;
            const float* src = U + (size_t)(r0 + row) * m + k0 + c0;
            *(float4*)(ut + row * 64 + c0) = *(const float4*)src;
            *(float4*)(ut + row * 64 + c0 + 4) = *(const float4*)(src + 4);
        }
        {
            int kk = t >> 3, c0 = (t & 7) * 4;
            *(float4*)(xt + kk * 32 + c0) =
                *(const float4*)(xw + (size_t)(k0 + kk) * 32 + c0);
        }
        __syncthreads();
#pragma unroll
        for (int kk = 0; kk < 64; kk++) {
            float xv = xt[kk * 32 + f];
            a0 += ut[rg * 64 + kk] * xv;
            a1 += ut[(rg + 16) * 64 + kk] * xv;
            a2 += ut[(rg + 32) * 64 + kk] * xv;
            a3 += ut[(rg + 48) * 64 + kk] * xv;
        }
        __syncthreads();
    }
    y[(size_t)(r0 + rg) * 32 + f] = a0;
    y[(size_t)(r0 + rg + 16) * 32 + f] = a1;
    y[(size_t)(r0 + rg + 32) * 32 + f] = a2;
    y[(size_t)(r0 + rg + 48) * 32 + f] = a3;
}

// ================= D1: mv[0:191) | bucket-fill | lin+U3  (256) ============
__global__ void __launch_bounds__(256) k_d1(Params P) {
    __shared__ float sm[2304];
    int bid = blockIdx.x;
    if (bid < 191)      matvec_y<true>(P, bid, sm);
    else if (bid < 255) fill_edges(P, bid - 191, 64);
    else                lin_u3(P, sm);
}

// ================= D2: mv[191:443) | g_g0(A3)  (256) ============
__global__ void __launch_bounds__(256) k_d2(Params P) {
    __shared__ float sm[2304];
    int bid = blockIdx.x;
    float* ws = P.ws;
    if (bid < 252) {
        matvec_y<false>(P, 191 + bid, sm);
    } else {
        const int* cnt = (int*)(ws + O_CNT);
        const int* bk  = (int*)(ws + O_BK);
        gatherB<4>(cnt + 21504, bk + 688128, ws + O_YG0, P.bg, N3,
                   ws + O_XG1, ws + O_STAT, bid - 252, 4, sm);
    }
}

// ================= D3: mv[443:512) | bn_g0  (70) ============
__global__ void __launch_bounds__(256) k_d3(Params P) {
    __shared__ float sm[2304];
    int bid = blockIdx.x;
    if (bid < 69) matvec_y<false>(P, 443 + bid, sm);
    else          bnxw256_g0(P, sm);
}

// ================= D4: g_l0 | gemmU2  (256 x 512) ============
__global__ void __launch_bounds__(512) k_d4(Params P) {
    __shared__ float sm[6144];
    int bid = blockIdx.x;
    float* ws = P.ws;
    const int* cnt = (int*)(ws + O_CNT);
    const int* bk  = (int*)(ws + O_BK);
    if (bid < 240)
        gatherB<8>(cnt, bk, ws + O_YL0, P.bl, N0, ws + O_XL1,
                   ws + O_STAT + 192, bid, 240, sm);
    else
        gemm512(P.U2, ws + O_XWG1, 256, ws + O_YG1, bid - 240, sm);
}

// ================= D5: bn_l0 | g_g1(A2)  (48 x 512) ============
__global__ void __launch_bounds__(512) k_d5(Params P) {
    __shared__ float sm[1152];
    int bid = blockIdx.x;
    float* ws = P.ws;
    const int* cnt = (int*)(ws + O_CNT);
    const int* bk  = (int*)(ws + O_BK);
    if (bid < 32)
        bnxw512<32>(ws + O_XL1, ws + O_STAT + 192, P.gam_l, P.bet_l, P.Wl + 1024,
                    1.f / N0, N0, ws + O_YL1, bid, sm);
    else
        gatherB<8>(cnt + 20480, bk + 655360, ws + O_YG1, P.bg + 32, N2,
                   ws + O_XG2, ws + O_STAT + 64, bid - 32, 16, sm);
}

// ================= D6: g_l1 | bn_g1  (242 x 512) ============
__global__ void __launch_bounds__(512) k_d6(Params P) {
    __shared__ float sm[1152];
    int bid = blockIdx.x;
    float* ws = P.ws;
    const int* cnt = (int*)(ws + O_CNT);
    const int* bk  = (int*)(ws + O_BK);
    if (bid < 240)
        gatherB<8>(cnt, bk, ws + O_YL1, P.bl + 32, N0, ws + O_XL2,
                   ws + O_STAT + 256, bid, 240, sm);
    else
        bnxw512<32>(ws + O_XG2, ws + O_STAT + 64, P.gam_g + 32, P.bet_g + 32,
                    P.Wg + 2048, 1.f / N2, N2, ws + O_XWG2, bid - 240, sm);
}

// ================= D7: bn_l1 | gemmU1  (96 x 512) ============
__global__ void __launch_bounds__(512) k_d7(Params P) {
    __shared__ float sm[6144];
    int bid = blockIdx.x;
    float* ws = P.ws;
    if (bid < 32)
        bnxw512<32>(ws + O_XL2, ws + O_STAT + 256, P.gam_l + 32, P.bet_l + 32,
                    P.Wl + 2048, 1.f / N0, N0, ws + O_YL2, bid, sm);
    else
        gemm512(P.U1, ws + O_XWG2, 1024, ws + O_YG2, bid - 32, sm);
}

// ================= D8: g_l2 | g_g2(A1)  (256 x 512) ============
__global__ void __launch_bounds__(512) k_d8(Params P) {
    __shared__ float sm[64];
    int bid = blockIdx.x;
    float* ws = P.ws;
    const int* cnt = (int*)(ws + O_CNT);
    const int* bk  = (int*)(ws + O_BK);
    if (bid < 240)
        gatherB<8>(cnt, bk, ws + O_YL2, P.bl + 64, N0, ws + O_XL3,
                   ws + O_STAT + 320, bid, 240, sm);
    else
        gatherB<8>(cnt + 16384, bk + 524288, ws + O_YG2, P.bg + 64, N1,
                   ws + O_XG3, ws + O_STAT + 128, bid - 240, 16, sm);
}

// ================= D9: bn_l2 (FO=3) | bn_g2 (FO=3)  (40 x 512) ============
__global__ void __launch_bounds__(512) k_d9(Params P) {
    __shared__ float sm[256];
    int bid = blockIdx.x;
    float* ws = P.ws;
    if (bid < 32)
        bnxw512<3>(ws + O_XL3, ws + O_STAT + 320, P.gam_l + 64, P.bet_l + 64,
                   P.Wl3, 1.f / N0, N0, ws + O_YL3, bid, sm);
    else
        bnxw512<3>(ws + O_XG3, ws + O_STAT + 128, P.gam_g + 64, P.bet_g + 64,
                   P.Wg3, 1.f / N1, N1, ws + O_XW3, bid - 32, sm);
}

// ================= D10: yg3 = U0 @ xw3  (256 x 256, 64 rows/block) ============
__global__ void __launch_bounds__(256) k_d10(Params P) {
    __shared__ float pl[12288];
    int t = threadIdx.x;
    const float* xw3 = P.ws + O_XW3;
    float* y = P.ws + O_YG3;
    for (int i = t; i < 12288; i += 256) {
        int k = i / 3, h = i - 3 * k;
        pl[h * 4096 + ((k & 3) << 10) + (k >> 2)] = xw3[i];
    }
    __syncthreads();
    int w = t >> 6, lane = t & 63;
    for (int it = 0; it < 4; it++) {
        for (int rr = 0; rr < 4; rr++) {
            int row = it * 4096 + blockIdx.x * 16 + w * 4 + rr;
            const float4* up = (const float4*)(P.U0 + (size_t)row * 4096);
            float a0 = 0, a1 = 0, a2 = 0;
#pragma unroll 4
            for (int c = 0; c < 16; c++) {
                float4 u = up[c * 64 + lane];
                int b = c * 64 + lane;
                a0 += u.x * pl[b]        + u.y * pl[1024 + b]  + u.z * pl[2048 + b]   + u.w * pl[3072 + b];
                a1 += u.x * pl[4096 + b] + u.y * pl[5120 + b]  + u.z * pl[6144 + b]   + u.w * pl[7168 + b];
                a2 += u.x * pl[8192 + b] + u.y * pl[9216 + b]  + u.z * pl[10240 + b]  + u.w * pl[11264 + b];
            }
            for (int o = 32; o; o >>= 1) {
                a0 += __shfl_down(a0, o, 64);
                a1 += __shfl_down(a1, o, 64);
                a2 += __shfl_down(a2, o, 64);
            }
            if (lane == 0) { y[row * 3] = a0; y[row * 3 + 1] = a1; y[row * 3 + 2] = a2; }
        }
    }
}

// ================= D11: final combine over A0 buckets  (256 x 256) ============
__global__ void __launch_bounds__(256) k_d11(Params P) {
    int t = blockIdx.x * 256 + threadIdx.x;
    int node = t >> 2, r = t & 3;
    if (node >= N0 || r >= 3) return;
    float* ws = P.ws;
    const int* cnt = (int*)(ws + O_CNT);
    const int* bk  = (int*)(ws + O_BK);
    const float* yg = ws + O_YG3;
    const float* yl = ws + O_YL3;
    int c = cnt[node];
    int cl = c < 32 ? c : 32;
    const int* b = bk + (size_t)node * 32;
    float ag = yg[node * 3 + r], al = yl[node * 3 + r];
    for (int e = 0; e < cl; e++) {
        int s = b[e];
        ag += yg[s * 3 + r];
        al += yl[s * 3 + r];
    }
    float inv = 1.f / (float)(c + 1);
    P.out[node * 3 + r] = 0.01f * (ag * inv + P.bg3[r]) + 0.99f * (al * inv + P.bl3[r]);
}

extern "C" void kernel_launch(void* const* d_in, const int* in_sizes, int n_in,
                              void* d_out, int out_size, void* d_ws, size_t ws_size,
                              hipStream_t stream) {
    Params p;
    p.z     = (const float*)d_in[0];
    p.lin_w = (const float*)d_in[1];
    p.lin_b = (const float*)d_in[2];
    p.loc_w = (const float*)d_in[3];
    p.loc_b = (const float*)d_in[4];
    p.Wg    = (const float*)d_in[5];
    p.bg    = (const float*)d_in[8];
    p.Wg3   = (const float*)d_in[9];
    p.bg3   = (const float*)d_in[12];
    p.Wl    = (const float*)d_in[13];
    p.bl    = (const float*)d_in[16];
    p.Wl3   = (const float*)d_in[17];
    p.bl3   = (const float*)d_in[20];
    p.gam_g = (const float*)d_in[21];
    p.bet_g = (const float*)d_in[22];
    p.gam_l = (const float*)d_in[23];
    p.bet_l = (const float*)d_in[24];
    p.U0    = (const float*)d_in[25];
    p.U1    = (const float*)d_in[26];
    p.U2    = (const float*)d_in[27];
    p.U3    = (const float*)d_in[28];
    p.A0    = (const int*)d_in[29];
    p.A1    = (const int*)d_in[30];
    p.A2    = (const int*)d_in[31];
    p.A3    = (const int*)d_in[32];
    p.ws    = (float*)d_ws;
    p.out   = (float*)d_out;

    hipMemsetAsync(d_ws, 0, (21760 + 384) * 4, stream);  // cnt + stats
    k_d1 <<<256, 256, 0, stream>>>(p);
    k_d2 <<<256, 256, 0, stream>>>(p);
    k_d3 <<<70,  256, 0, stream>>>(p);
    k_d4 <<<256, 512, 0, stream>>>(p);
    k_d5 <<<48,  512, 0, stream>>>(p);
    k_d6 <<<242, 512, 0, stream>>>(p);
    k_d7 <<<96,  512, 0, stream>>>(p);
    k_d8 <<<256, 512, 0, stream>>>(p);
    k_d9 <<<40,  512, 0, stream>>>(p);
    k_d10<<<256, 256, 0, stream>>>(p);
    k_d11<<<256, 256, 0, stream>>>(p);
}